// Round 5
// baseline (1334.519 us; speedup 1.0000x reference)
//
#include <hip/hip_runtime.h>
#include <hip/hip_bf16.h>

#define NTOK 577
#define CH 768
#define NH 12
#define HD 64
#define M_ROWS 9232      // B * N
#define MPV 640          // m pitch of vT (5 * 128)

#define XHE 7090176      // M_ROWS * CH
#define WQH 1769472      // 3 * CH * CH
#define WPH 589824       // CH * CH

typedef _Float16 f16x8 __attribute__((ext_vector_type(8)));
typedef _Float16 f16x4 __attribute__((ext_vector_type(4)));
typedef _Float16 f16x2 __attribute__((ext_vector_type(2)));
typedef float f32x4 __attribute__((ext_vector_type(4)));

#define MFMA16(a, b, c) __builtin_amdgcn_mfma_f32_16x16x32_f16((a), (b), (c), 0, 0, 0)

// async global->LDS, 16 B per lane. LDS dest must be wave-linear (base+lane*16).
#define GLD16(gp, lp) __builtin_amdgcn_global_load_lds(               \
    (const __attribute__((address_space(1))) void*)(gp),              \
    (__attribute__((address_space(3))) void*)(lp), 16, 0, 0)

// XCD-chunked bijective swizzle (m204)
__device__ __forceinline__ int xcd_swz(int lin, int G) {
  int q = G >> 3, r = G & 7;
  int x = lin & 7, i = lin >> 3;
  return (x < r ? x * (q + 1) : r * (q + 1) + (x - r) * q) + i;
}

__device__ __forceinline__ float bf2f(unsigned int u16) {
  union { unsigned int i; float f; } x; x.i = u16 << 16; return x.f;
}

__device__ __forceinline__ float ldin(const void* p, size_t i, bool f32) {
  return f32 ? ((const float*)p)[i]
             : __bfloat162float(((const __hip_bfloat16*)p)[i]);
}

__device__ __forceinline__ f16x8 ld8_cvt(const void* p, size_t idx, bool f32) {
  f16x8 r;
  if (f32) {
    const float* f = (const float*)p + idx;
    const float4 u = *(const float4*)f;
    const float4 v = *(const float4*)(f + 4);
    r[0]=(_Float16)u.x; r[1]=(_Float16)u.y; r[2]=(_Float16)u.z; r[3]=(_Float16)u.w;
    r[4]=(_Float16)v.x; r[5]=(_Float16)v.y; r[6]=(_Float16)v.z; r[7]=(_Float16)v.w;
  } else {
    const unsigned short* s = (const unsigned short*)p + idx;
    uint4 u = *(const uint4*)s;
    unsigned int w0=u.x, w1=u.y, w2=u.z, w3=u.w;
    r[0]=(_Float16)bf2f(w0&0xffffu); r[1]=(_Float16)bf2f(w0>>16);
    r[2]=(_Float16)bf2f(w1&0xffffu); r[3]=(_Float16)bf2f(w1>>16);
    r[4]=(_Float16)bf2f(w2&0xffffu); r[5]=(_Float16)bf2f(w2>>16);
    r[6]=(_Float16)bf2f(w3&0xffffu); r[7]=(_Float16)bf2f(w3>>16);
  }
  return r;
}

// ---- Kernel 0: detect input dtype (fp32 vs bf16).
__global__ void detect_dtype(const unsigned short* __restrict__ xs,
                             int* __restrict__ flag) {
  __shared__ int cnt;
  if (threadIdx.x == 0) cnt = 0;
  __syncthreads();
  int local = 0;
  for (int i = threadIdx.x; i < 4096; i += 256) {
    unsigned int u = xs[2 * i];
    unsigned int e = (u >> 7) & 0xFFu;
    if (e >= 140u) local++;
  }
  atomicAdd(&cnt, local);
  __syncthreads();
  if (threadIdx.x == 0) *flag = (cnt > 100) ? 1 : 0;
}

// ---- Kernel 0b: convert x | Wqkv | Wproj into one contiguous f16 region.
__global__ __launch_bounds__(256) void cvt_all(
    const void* __restrict__ x, const void* __restrict__ wq,
    const void* __restrict__ wp, _Float16* __restrict__ dst,
    const int* __restrict__ flagp)
{
  const bool f32 = (*flagp != 0);
  size_t i = (size_t)(blockIdx.x * 256 + threadIdx.x) * 8;
  if (i >= (size_t)(XHE + WQH + WPH)) return;
  const void* src; size_t off;
  if (i < XHE)            { src = x;  off = i; }
  else if (i < XHE + WQH) { src = wq; off = i - XHE; }
  else                    { src = wp; off = i - XHE - WQH; }
  *(f16x8*)(dst + i) = ld8_cvt(src, off, f32);
}

// ---- Kernel 1: qkv = x @ Wqkv^T, m97 structure: global_load_lds width-16
// into linear [128][32] double-buffered LDS, source-side XOR swizzle.
__global__ __launch_bounds__(256) void gemm_qkv_mfma(
    const _Float16* __restrict__ X, const _Float16* __restrict__ W,
    _Float16* __restrict__ q, _Float16* __restrict__ k,
    _Float16* __restrict__ vT)
{
  __shared__ __align__(16) _Float16 As[2][128 * 32];
  __shared__ __align__(16) _Float16 Bs[2][128 * 32];
  const int swz = xcd_swz(blockIdx.x, 18 * 73);
  const int bx = swz % 18;                 // output-col tile (fast: shares X)
  const int m0 = (swz / 18) * 128;
  const int tid = threadIdx.x;
  const int lane = tid & 63, wave = tid >> 6;
  const int quad = lane >> 4, l16 = lane & 15;
  const int wm = wave & 1, wo = wave >> 1;
  const int t = bx / 6;                    // 0=q 1=k 2=v
  const int o0 = bx * 128;
  const int o0loc = o0 - t * CH;

  const int row0 = wave * 32 + (lane >> 2);
  const int ch8  = (((lane & 3) ^ ((lane >> 3) & 3)) << 3);  // swizzled src col
  const int ar0 = min(m0 + row0, M_ROWS - 1);
  const int ar1 = min(m0 + row0 + 16, M_ROWS - 1);
  const int br0 = o0 + row0;
  const int br1 = o0 + row0 + 16;
  const int dl0 = wave * 1024 + lane * 8;   // linear LDS dest (f16 idx)
  const int dl1 = dl0 + 512;

  GLD16(X + (size_t)ar0 * CH + ch8, &As[0][dl0]);
  GLD16(X + (size_t)ar1 * CH + ch8, &As[0][dl1]);
  GLD16(W + (size_t)br0 * CH + ch8, &Bs[0][dl0]);
  GLD16(W + (size_t)br1 * CH + ch8, &Bs[0][dl1]);

  const int rdc = ((quad ^ ((l16 >> 1) & 3)) << 3);      // swizzled read col
  const int rdA = (wm * 64 + l16) * 32 + rdc;
  const int rdB = (wo * 64 + l16) * 32 + rdc;

  f32x4 acc[4][4] = {};
  int cur = 0;
  for (int ks = 0; ks < CH / 32; ++ks) {
    __syncthreads();                       // drains vmcnt: tile ks ready
    if (ks + 1 < CH / 32) {
      const int kc = (ks + 1) * 32 + ch8;
      const int nb = cur ^ 1;
      GLD16(X + (size_t)ar0 * CH + kc, &As[nb][dl0]);
      GLD16(X + (size_t)ar1 * CH + kc, &As[nb][dl1]);
      GLD16(W + (size_t)br0 * CH + kc, &Bs[nb][dl0]);
      GLD16(W + (size_t)br1 * CH + kc, &Bs[nb][dl1]);
    }
    f16x8 af[4], bf_[4];
    #pragma unroll
    for (int i = 0; i < 4; ++i)
      af[i] = *(const f16x8*)&As[cur][rdA + i * 512];
    #pragma unroll
    for (int j = 0; j < 4; ++j)
      bf_[j] = *(const f16x8*)&Bs[cur][rdB + j * 512];
    #pragma unroll
    for (int i = 0; i < 4; ++i)
      #pragma unroll
      for (int j = 0; j < 4; ++j)
        acc[i][j] = MFMA16(af[i], bf_[j], acc[i][j]);
    cur ^= 1;
  }

  if (t < 2) {
    #pragma unroll
    for (int i = 0; i < 4; ++i) {
      #pragma unroll
      for (int rr = 0; rr < 4; ++rr) {
        int m = m0 + wm * 64 + i * 16 + quad * 4 + rr;
        if (m >= M_ROWS) continue;
        int b = m / NTOK, n = m - b * NTOK;
        #pragma unroll
        for (int j = 0; j < 4; ++j) {
          int o = o0loc + wo * 64 + j * 16 + l16;
          int h = o >> 6, dd = o & 63;
          _Float16 val = (_Float16)acc[i][j][rr];
          if (t == 0)
            q[((size_t)(b * NH + h) * NTOK + n) * HD + dd] = val;
          else
            k[((size_t)(b * NH + h) * NTOK + n) * HD + dd] = val;
        }
      }
    }
  } else {
    // vT epilogue: per-wave LDS micro-transpose of each 16x16 fragment.
    __syncthreads();                       // LDS reads of K-loop done
    _Float16* scrb = &As[0][0] + wave * 512;
    #pragma unroll
    for (int i = 0; i < 4; ++i) {
      #pragma unroll
      for (int j = 0; j < 4; ++j) {
        _Float16* scr = scrb + (j & 1) * 256;
        f16x4 wv;
        wv[0] = (_Float16)acc[i][j][0]; wv[1] = (_Float16)acc[i][j][1];
        wv[2] = (_Float16)acc[i][j][2]; wv[3] = (_Float16)acc[i][j][3];
        *(f16x4*)&scr[l16 * 16 + quad * 4] = wv;   // scr[dd][n_loc]
        asm volatile("s_waitcnt lgkmcnt(0)" ::: "memory");
        f16x4 rv = *(const f16x4*)&scr[(lane >> 2) * 16 + (lane & 3) * 4];
        int oc = o0loc + wo * 64 + j * 16 + (lane >> 2);
        int hh = oc >> 6, ddg = oc & 63;
        int mbase = m0 + wm * 64 + i * 16 + (lane & 3) * 4;
        int bb = mbase / NTOK, nn = mbase - bb * NTOK;
        _Float16* dst = &vT[((size_t)(bb * NH + hh) * HD + ddg) * MPV + nn];
        if (mbase + 3 < M_ROWS && nn + 3 < NTOK && !(nn & 1)) {
          f16x2 lo2, hi2;
          lo2[0] = rv[0]; lo2[1] = rv[1];
          hi2[0] = rv[2]; hi2[1] = rv[3];
          *(f16x2*)dst = lo2;
          *(f16x2*)(dst + 2) = hi2;
        } else {
          #pragma unroll
          for (int e = 0; e < 4; ++e) {
            int m = mbase + e;
            if (m < M_ROWS) {
              int b2 = m / NTOK, n2 = m - b2 * NTOK;
              vT[((size_t)(b2 * NH + hh) * HD + ddg) * MPV + n2] = rv[e];
            }
          }
        }
      }
    }
  }
}

// ---- zero the m-pad of vT (m in [577,640)).
__global__ void zerofill_vt(_Float16* __restrict__ vT) {
  int idx = blockIdx.x * 256 + threadIdx.x;
  int r = idx >> 6, c = idx & 63;
  if (r < 16 * NH * HD && c < MPV - NTOK)
    vT[(size_t)r * MPV + NTOK + c] = (_Float16)0.f;
}

// ---- Kernel 2 (fused attention): per (batch, 8-row n-tile) block.
// Pass 1: QK^T + Wpre mix + exp -> E in LDS (ONCE; round-1's failure was
// recomputing it) + register rowsum partials. Pass 2: normalize + Wpost mix
// + PV -> o1 f16 direct. No E/Rp/Op HBM traffic, no reduce kernel.
// E tile [12][8][648] f16: pitch 648 f16 = 1296 B => row n starts 4 banks
// after row n-1, so the pass-2 read (8 rows x 16 B per quarter-wave) is
// bank-conflict-free. LDS total 142.5 KB -> dynamic shared (1 block/CU,
// 8 waves = 2/SIMD).
__global__ __launch_bounds__(512, 1) void attn_fused(
    const _Float16* __restrict__ q, const _Float16* __restrict__ k,
    const _Float16* __restrict__ vT, const void* __restrict__ Wpre,
    const void* __restrict__ Wpost, const int* __restrict__ flagp,
    _Float16* __restrict__ o1)
{
  extern __shared__ __align__(16) char smem[];
  _Float16* Eg   = (_Float16*)smem;                     // [12][8][648]
  _Float16* qs   = Eg + 12 * 8 * 648;                   // [12][8][72]
  float*    wsum = (float*)(qs + 12 * 8 * 72);          // [8][12][8]
  float*    wp   = wsum + 8 * 12 * 8;                   // [144]
  _Float16* w2h  = (_Float16*)(wp + 144);               // [144]
  float*    rinv = (float*)(w2h + 144);                 // [12][8]

  const bool f32 = (*flagp != 0);
  const int tid = threadIdx.x;
  const int swzb = xcd_swz(blockIdx.x, 16 * 73);
  const int b = swzb / 73;                 // same-batch blocks contiguous
  const int n0 = (swzb % 73) * 8;
  const int lane = tid & 63, w = tid >> 6;
  const int quad = lane >> 4, l16 = lane & 15;
  const int nloc = l16 & 7;

  if (tid < 144) {
    wp[tid]  = ldin(Wpre, tid, f32) * 0.125f;           // fold d^-0.5
    w2h[tid] = (_Float16)ldin(Wpost, tid, f32);
  }
  // stage q tile: 12h x 8n x 64d (rows >= NTOK clamped; outputs masked later)
  for (int t = tid; t < 768; t += 512) {
    int h = t >> 6, n = (t >> 3) & 7, c = t & 7;
    int gn = min(n0 + n, NTOK - 1);
    *(f16x8*)&qs[h * 576 + n * 72 + c * 8] =
        *(const f16x8*)(q + ((size_t)(b * NH + h) * NTOK + gn) * HD + c * 8);
  }
  __syncthreads();

  // ---- pass 1: wave w owns m in [w*80, w*80+80)
  float rs[NH][4];
  #pragma unroll
  for (int g = 0; g < NH; ++g)
    #pragma unroll
    for (int r = 0; r < 4; ++r) rs[g][r] = 0.f;

  const int mw0 = w * 80;
  for (int mt = 0; mt < 5; ++mt) {
    const int m = mw0 + mt * 16 + l16;
    const int mk = min(m, NTOK - 1);
    f32x4 acc[NH];
    #pragma unroll
    for (int h = 0; h < NH; ++h) {
      f16x8 q0 = *(const f16x8*)&qs[h * 576 + nloc * 72 + quad * 8];
      f16x8 q1 = *(const f16x8*)&qs[h * 576 + nloc * 72 + quad * 8 + 32];
      const _Float16* kp = k + ((size_t)(b * NH + h) * NTOK + mk) * HD + quad * 8;
      f16x8 k0 = *(const f16x8*)kp;
      f16x8 k1 = *(const f16x8*)(kp + 32);
      f32x4 z = {0.f, 0.f, 0.f, 0.f};
      z = MFMA16(q0, k0, z);
      acc[h] = MFMA16(q1, k1, z);      // C[n=quad*4+r][m=l16]; rows 8..15 dup
    }
    const bool vm = (m < NTOK);
    #pragma unroll
    for (int g = 0; g < NH; ++g) {
      float s0 = 0.f, s1 = 0.f, s2 = 0.f, s3 = 0.f;
      #pragma unroll
      for (int h = 0; h < NH; ++h) {
        const float ww = wp[g * NH + h];
        s0 += ww * acc[h][0]; s1 += ww * acc[h][1];
        s2 += ww * acc[h][2]; s3 += ww * acc[h][3];
      }
      float e0 = vm ? __expf(s0) : 0.f;
      float e1 = vm ? __expf(s1) : 0.f;
      float e2 = vm ? __expf(s2) : 0.f;
      float e3 = vm ? __expf(s3) : 0.f;
      if (quad < 2) {                      // rows n = quad*4 .. +3 (valid < 8)
        _Float16* er = &Eg[g * 5184 + (quad * 4) * 648 + m];
        er[0]    = (_Float16)e0;
        er[648]  = (_Float16)e1;
        er[1296] = (_Float16)e2;
        er[1944] = (_Float16)e3;
      }
      rs[g][0] += e0; rs[g][1] += e1; rs[g][2] += e2; rs[g][3] += e3;
    }
  }
  #pragma unroll
  for (int g = 0; g < NH; ++g)
    #pragma unroll
    for (int r = 0; r < 4; ++r) {
      float t = rs[g][r];
      t += __shfl_xor(t, 1); t += __shfl_xor(t, 2);
      t += __shfl_xor(t, 4); t += __shfl_xor(t, 8);
      rs[g][r] = t;
    }
  if (l16 == 0 && quad < 2) {
    #pragma unroll
    for (int g = 0; g < NH; ++g)
      #pragma unroll
      for (int r = 0; r < 4; ++r)
        wsum[(w * NH + g) * 8 + quad * 4 + r] = rs[g][r];
  }
  __syncthreads();
  if (tid < 96) {
    int g = tid >> 3, n = tid & 7;
    float S = 0.f;
    #pragma unroll
    for (int ww = 0; ww < 8; ++ww) S += wsum[(ww * NH + g) * 8 + n];
    rinv[g * 8 + n] = (S > 0.f) ? 1.f / S : 0.f;
  }
  __syncthreads();

  // ---- pass 2: wave w -> g in [gB, gB+3), d-half dh
  const int gB = (w >> 1) * 3, dh = w & 1;
  _Float16 rl[NH];
  #pragma unroll
  for (int h = 0; h < NH; ++h) rl[h] = (_Float16)rinv[h * 8 + nloc];
  f32x4 O[3][2];
  #pragma unroll
  for (int j = 0; j < 3; ++j) {
    O[j][0] = (f32x4){0.f, 0.f, 0.f, 0.f};
    O[j][1] = (f32x4){0.f, 0.f, 0.f, 0.f};
  }
  for (int kc = 0; kc < 20; ++kc) {
    const int mo = kc * 32 + quad * 8;
    f16x8 evn[NH];
    #pragma unroll
    for (int h = 0; h < NH; ++h)
      evn[h] = (*(const f16x8*)&Eg[h * 5184 + nloc * 648 + mo]) * rl[h];
    #pragma unroll
    for (int j = 0; j < 3; ++j) {
      const int g = gB + j;
      f16x8 p = evn[0] * w2h[g * NH + 0];
      #pragma unroll
      for (int h = 1; h < NH; ++h) p += evn[h] * w2h[g * NH + h];
      #pragma unroll
      for (int dtl = 0; dtl < 2; ++dtl) {
        const int dt = dh * 2 + dtl;
        f16x8 bv = *(const f16x8*)(
            vT + ((size_t)(b * NH + g) * HD + dt * 16 + l16) * MPV + mo);
        O[j][dtl] = MFMA16(p, bv, O[j][dtl]);   // C[n=quad*4+r][d=l16]
      }
    }
  }
  #pragma unroll
  for (int j = 0; j < 3; ++j)
    #pragma unroll
    for (int dtl = 0; dtl < 2; ++dtl)
      #pragma unroll
      for (int r = 0; r < 4; ++r) {
        int n = quad * 4 + r;
        if (n < 8 && n0 + n < NTOK)
          o1[((size_t)b * NTOK + n0 + n) * CH + (gB + j) * HD
             + (dh * 2 + dtl) * 16 + l16] = (_Float16)O[j][dtl][r];
      }
}

// ---- Kernel 4: out = o1 @ Wproj^T + bproj, m97-style staging.
__global__ __launch_bounds__(256) void gemm_proj_mfma(
    const _Float16* __restrict__ A, const _Float16* __restrict__ W,
    const void* __restrict__ bias, const int* __restrict__ flagp,
    void* __restrict__ out)
{
  const bool f32 = (*flagp != 0);
  __shared__ __align__(16) _Float16 As[2][128 * 32];
  __shared__ __align__(16) _Float16 Bs[2][128 * 32];
  const int swz = xcd_swz(blockIdx.x, 6 * 73);
  const int o0 = (swz % 6) * 128;
  const int m0 = (swz / 6) * 128;
  const int tid = threadIdx.x;
  const int lane = tid & 63, wave = tid >> 6;
  const int quad = lane >> 4, l16 = lane & 15;
  const int wm = wave & 1, wo = wave >> 1;

  const int row0 = wave * 32 + (lane >> 2);
  const int ch8  = (((lane & 3) ^ ((lane >> 3) & 3)) << 3);
  const int ar0 = min(m0 + row0, M_ROWS - 1);
  const int ar1 = min(m0 + row0 + 16, M_ROWS - 1);
  const int br0 = o0 + row0;
  const int br1 = o0 + row0 + 16;
  const int dl0 = wave * 1024 + lane * 8;
  const int dl1 = dl0 + 512;

  GLD16(A + (size_t)ar0 * CH + ch8, &As[0][dl0]);
  GLD16(A + (size_t)ar1 * CH + ch8, &As[0][dl1]);
  GLD16(W + (size_t)br0 * CH + ch8, &Bs[0][dl0]);
  GLD16(W + (size_t)br1 * CH + ch8, &Bs[0][dl1]);

  const int rdc = ((quad ^ ((l16 >> 1) & 3)) << 3);
  const int rdA = (wm * 64 + l16) * 32 + rdc;
  const int rdB = (wo * 64 + l16) * 32 + rdc;

  f32x4 acc[4][4] = {};
  int cur = 0;
  for (int ks = 0; ks < CH / 32; ++ks) {
    __syncthreads();
    if (ks + 1 < CH / 32) {
      const int kc = (ks + 1) * 32 + ch8;
      const int nb = cur ^ 1;
      GLD16(A + (size_t)ar0 * CH + kc, &As[nb][dl0]);
      GLD16(A + (size_t)ar1 * CH + kc, &As[nb][dl1]);
      GLD16(W + (size_t)br0 * CH + kc, &Bs[nb][dl0]);
      GLD16(W + (size_t)br1 * CH + kc, &Bs[nb][dl1]);
    }
    f16x8 af[4], bf_[4];
    #pragma unroll
    for (int i = 0; i < 4; ++i)
      af[i] = *(const f16x8*)&As[cur][rdA + i * 512];
    #pragma unroll
    for (int j = 0; j < 4; ++j)
      bf_[j] = *(const f16x8*)&Bs[cur][rdB + j * 512];
    #pragma unroll
    for (int i = 0; i < 4; ++i)
      #pragma unroll
      for (int j = 0; j < 4; ++j)
        acc[i][j] = MFMA16(af[i], bf_[j], acc[i][j]);
    cur ^= 1;
  }

  #pragma unroll
  for (int i = 0; i < 4; ++i) {
    #pragma unroll
    for (int rr = 0; rr < 4; ++rr) {
      int m = m0 + wm * 64 + i * 16 + quad * 4 + rr;
      if (m >= M_ROWS) continue;
      #pragma unroll
      for (int j = 0; j < 4; ++j) {
        int o = o0 + wo * 64 + j * 16 + l16;
        float val = acc[i][j][rr] + ldin(bias, o, f32);
        if (f32) ((float*)out)[(size_t)m * CH + o] = val;
        else ((__hip_bfloat16*)out)[(size_t)m * CH + o] = __float2bfloat16(val);
      }
    }
  }
}

extern "C" void kernel_launch(void* const* d_in, const int* in_sizes, int n_in,
                              void* d_out, int out_size, void* d_ws, size_t ws_size,
                              hipStream_t stream) {
  const void* x     = d_in[0];
  const void* Wqkv  = d_in[1];
  const void* Wproj = d_in[2];
  const void* bproj = d_in[3];
  const void* Wpre  = d_in[4];
  const void* Wpost = d_in[5];

  int* flag = (int*)d_ws;
  _Float16* ws = (_Float16*)((char*)d_ws + 16);
  const size_t QE  = (size_t)16 * NH * NTOK * HD;   // 7,090,176
  const size_t VTE = (size_t)16 * NH * HD * MPV;    // 7,864,320

  _Float16* Xh  = ws;
  _Float16* Wqh = Xh + XHE;
  _Float16* Wph = Wqh + WQH;
  _Float16* q   = Wph + WPH;
  _Float16* k   = q + QE;
  _Float16* vT  = k + QE;
  _Float16* o1  = vT + VTE;

  // attn_fused LDS: Eg 124416 + qs 13824 + wsum 3072 + wp 576 + w2h 288
  //               + rinv 384 = 142,560 B  (> 64 KB static limit -> dynamic)
  const size_t SMEM = 142560;
  hipFuncSetAttribute((const void*)attn_fused,
                      hipFuncAttributeMaxDynamicSharedMemorySize, (int)SMEM);

  dim3 blk(256);
  hipLaunchKernelGGL(detect_dtype, dim3(1), blk, 0, stream,
                     (const unsigned short*)x, flag);
  hipLaunchKernelGGL(cvt_all, dim3((XHE + WQH + WPH) / 8 / 256 + 1), blk, 0,
                     stream, x, Wqkv, Wproj, Xh, flag);
  hipLaunchKernelGGL(gemm_qkv_mfma, dim3(18 * 73), blk, 0, stream,
                     Xh, Wqh, q, k, vT);
  hipLaunchKernelGGL(zerofill_vt, dim3(16 * NH * HD * 64 / 256), blk, 0, stream, vT);
  hipLaunchKernelGGL(attn_fused, dim3(16 * 73), dim3(512), SMEM, stream,
                     q, k, vT, Wpre, Wpost, flag, o1);
  hipLaunchKernelGGL(gemm_proj_mfma, dim3(6 * 73), blk, 0, stream,
                     o1, Wph, bproj, flag, d_out);
}